// Round 1
// baseline (468.450 us; speedup 1.0000x reference)
//
#include <hip/hip_runtime.h>
#include <math.h>

#define H_HEADS 33
#define C_CH    16
#define HC      528      // H_HEADS * C_CH
#define F_IN    128
#define NEG_SLOPE 0.2f

// ---------------------------------------------------------------------------
// K1: h = x @ W   (M=N nodes, K=128, N=528), fp32, 64x64 tiles, BK=32
// ---------------------------------------------------------------------------
__global__ __launch_bounds__(256) void gemm_kernel(
    const float* __restrict__ x, const float* __restrict__ W,
    float* __restrict__ h, int N)
{
    __shared__ float xs[64][33];   // [row][k], padded: read banks differ by 4 per ty
    __shared__ float ws[32][64];   // [k][col]

    const int tid = threadIdx.x;
    const int tx = tid & 15;       // col group (4 cols each)
    const int ty = tid >> 4;       // row group (4 rows each)
    const int row0 = blockIdx.x * 64;
    const int col0 = blockIdx.y * 64;

    float acc[4][4] = {};

    for (int kk = 0; kk < F_IN; kk += 32) {
        // stage x: 64 rows x 32 k  (consecutive tid -> consecutive k, 128B runs)
        for (int e = tid; e < 64 * 32; e += 256) {
            int r = e >> 5, k = e & 31;
            int gr = row0 + r;
            xs[r][k] = (gr < N) ? x[gr * F_IN + kk + k] : 0.0f;
        }
        // stage W: 32 k x 64 cols (coalesced 256B rows)
        for (int e = tid; e < 32 * 64; e += 256) {
            int k = e >> 6, c = e & 63;
            int gc = col0 + c;
            ws[k][c] = (gc < HC) ? W[(kk + k) * HC + gc] : 0.0f;
        }
        __syncthreads();

        #pragma unroll
        for (int k = 0; k < 32; ++k) {
            float a[4], b[4];
            #pragma unroll
            for (int i = 0; i < 4; ++i) a[i] = xs[ty * 4 + i][k];
            #pragma unroll
            for (int j = 0; j < 4; ++j) b[j] = ws[k][tx * 4 + j];
            #pragma unroll
            for (int i = 0; i < 4; ++i)
                #pragma unroll
                for (int j = 0; j < 4; ++j)
                    acc[i][j] += a[i] * b[j];
        }
        __syncthreads();
    }

    #pragma unroll
    for (int i = 0; i < 4; ++i) {
        int r = row0 + ty * 4 + i;
        if (r >= N) continue;
        #pragma unroll
        for (int j = 0; j < 4; ++j) {
            int c = col0 + tx * 4 + j;
            if (c < HC) h[r * HC + c] = acc[i][j];
        }
    }
}

// ---------------------------------------------------------------------------
// K1b: a_src[n,hd] = <h[n,hd,:], att_src[hd,:]>, same for a_dst
// ---------------------------------------------------------------------------
__global__ void att_kernel(const float* __restrict__ h,
                           const float* __restrict__ att_src,
                           const float* __restrict__ att_dst,
                           float* __restrict__ a_src, float* __restrict__ a_dst,
                           int total)  // total = N * H_HEADS
{
    int g = blockIdx.x * blockDim.x + threadIdx.x;
    if (g >= total) return;
    int n = g / H_HEADS, head = g % H_HEADS;
    const float4* hv  = (const float4*)(h + (size_t)n * HC + head * C_CH);
    const float4* asv = (const float4*)(att_src + head * C_CH);
    const float4* adv = (const float4*)(att_dst + head * C_CH);
    float s = 0.f, d = 0.f;
    #pragma unroll
    for (int q = 0; q < 4; ++q) {
        float4 hq = hv[q], aq = asv[q], bq = adv[q];
        s += hq.x * aq.x + hq.y * aq.y + hq.z * aq.z + hq.w * aq.w;
        d += hq.x * bq.x + hq.y * bq.y + hq.z * bq.z + hq.w * bq.w;
    }
    a_src[g] = s;
    a_dst[g] = d;
}

// ---------------------------------------------------------------------------
// K2: denom[dst,hd] += exp(leakyrelu(a_src[src,hd] + a_dst[dst,hd]))
//     NOTE: segment-max subtraction is skipped: |e| <~ 3.5 so exp() is safe,
//     and softmax is shift-invariant -> identical result.
//     One thread per (edge, head); consecutive lanes share an edge -> 132B
//     coalesced runs on a_src/a_dst/denom.
// ---------------------------------------------------------------------------
__global__ void denom_kernel(const int* __restrict__ ei,
                             const float* __restrict__ a_src,
                             const float* __restrict__ a_dst,
                             float* __restrict__ denom,
                             int E, int Et)
{
    int g = blockIdx.x * blockDim.x + threadIdx.x;
    if (g >= Et * H_HEADS) return;
    int e = g / H_HEADS, hd = g % H_HEADS;
    int src, dst;
    if (e < E) { src = ei[e]; dst = ei[E + e]; }
    else       { src = dst = e - E; }          // self loops appended
    float v = a_src[src * H_HEADS + hd] + a_dst[dst * H_HEADS + hd];
    v = v > 0.f ? v : NEG_SLOPE * v;
    atomicAdd(&denom[dst * H_HEADS + hd], __expf(v));
}

// K2b: denom -> 1/(denom + 1e-16) in place
__global__ void inv_kernel(float* __restrict__ denom, int total)
{
    int g = blockIdx.x * blockDim.x + threadIdx.x;
    if (g >= total) return;
    denom[g] = 1.0f / (denom[g] + 1e-16f);
}

// ---------------------------------------------------------------------------
// K3: out[dst,c] += sum_h alpha[e,h] * h[src,h,c]
//     One thread per (edge, channel). The mean-over-heads lets us reduce the
//     per-edge atomic payload from H*C=528 floats to C=16 floats.
// ---------------------------------------------------------------------------
__global__ void aggregate_kernel(const int* __restrict__ ei,
                                 const float* __restrict__ a_src,
                                 const float* __restrict__ a_dst,
                                 const float* __restrict__ inv_denom,
                                 const float* __restrict__ h,
                                 float* __restrict__ out,
                                 int E, int Et)
{
    int g = blockIdx.x * blockDim.x + threadIdx.x;
    if (g >= Et * C_CH) return;
    int e = g >> 4, c = g & 15;
    int src, dst;
    if (e < E) { src = ei[e]; dst = ei[E + e]; }
    else       { src = dst = e - E; }
    const float* as = a_src + src * H_HEADS;       // broadcast within 16-lane group
    const float* ad = a_dst + dst * H_HEADS;
    const float* id = inv_denom + dst * H_HEADS;
    const float* hs = h + (size_t)src * HC + c;    // 64B coalesced per head
    float acc = 0.f;
    #pragma unroll
    for (int hd = 0; hd < H_HEADS; ++hd) {
        float v = as[hd] + ad[hd];
        v = v > 0.f ? v : NEG_SLOPE * v;
        float alpha = __expf(v) * id[hd];
        acc += alpha * hs[hd * C_CH];
    }
    atomicAdd(&out[dst * C_CH + c], acc);
}

// K4: out = tanh(out/H + bias), in place
__global__ void finalize_kernel(float* __restrict__ out,
                                const float* __restrict__ bias, int total)
{
    int g = blockIdx.x * blockDim.x + threadIdx.x;
    if (g >= total) return;
    out[g] = tanhf(out[g] * (1.0f / 33.0f) + bias[g & 15]);
}

// ---------------------------------------------------------------------------
extern "C" void kernel_launch(void* const* d_in, const int* in_sizes, int n_in,
                              void* d_out, int out_size, void* d_ws, size_t ws_size,
                              hipStream_t stream)
{
    const float* x       = (const float*)d_in[0];
    const int*   ei      = (const int*)  d_in[1];
    const float* W       = (const float*)d_in[2];
    const float* att_src = (const float*)d_in[3];
    const float* att_dst = (const float*)d_in[4];
    const float* bias    = (const float*)d_in[5];
    float* out = (float*)d_out;

    const int N  = in_sizes[0] / F_IN;   // 50000
    const int E  = in_sizes[1] / 2;      // 320000
    const int Et = E + N;                // with self loops

    // workspace layout (fp32): h | a_src | a_dst | denom  (~125.4 MB)
    float* h      = (float*)d_ws;
    float* a_src  = h + (size_t)N * HC;
    float* a_dst  = a_src + (size_t)N * H_HEADS;
    float* denom  = a_dst + (size_t)N * H_HEADS;

    // d_out doubles as the atomic accumulator -> must be zeroed every call
    hipMemsetAsync(d_out, 0, (size_t)out_size * sizeof(float), stream);
    hipMemsetAsync(denom, 0, (size_t)N * H_HEADS * sizeof(float), stream);

    dim3 g1((N + 63) / 64, (HC + 63) / 64);
    gemm_kernel<<<g1, 256, 0, stream>>>(x, W, h, N);

    int totA = N * H_HEADS;
    att_kernel<<<(totA + 255) / 256, 256, 0, stream>>>(h, att_src, att_dst,
                                                       a_src, a_dst, totA);

    int totD = Et * H_HEADS;
    denom_kernel<<<(totD + 255) / 256, 256, 0, stream>>>(ei, a_src, a_dst,
                                                         denom, E, Et);

    inv_kernel<<<(totA + 255) / 256, 256, 0, stream>>>(denom, totA);

    int totG = Et * C_CH;
    aggregate_kernel<<<(totG + 255) / 256, 256, 0, stream>>>(ei, a_src, a_dst,
                                                             denom, h, out, E, Et);

    int totO = N * C_CH;
    finalize_kernel<<<(totO + 255) / 256, 256, 0, stream>>>(out, bias, totO);
}

// Round 2
// 374.180 us; speedup vs baseline: 1.2519x; 1.2519x over previous
//
#include <hip/hip_runtime.h>
#include <math.h>

#define H_HEADS 33
#define C_CH    16
#define HC      528      // H_HEADS * C_CH
#define F_IN    128
#define NEG_SLOPE 0.2f

typedef short  bf16x8  __attribute__((ext_vector_type(8)));
typedef float  floatx4 __attribute__((ext_vector_type(4)));

__device__ inline unsigned short f2bf(float f) {   // RNE float->bf16
    unsigned int u = __float_as_uint(f);
    unsigned int r = u + 0x7fffu + ((u >> 16) & 1u);
    return (unsigned short)(r >> 16);
}

// ---------------------------------------------------------------------------
// K1: h = x @ W  (M=N nodes, K=128, N=528) via bf16 MFMA 16x16x32.
// BM=64, BN=48 (528 = 11*48), full K=128 staged in LDS once per block.
// 4 waves: wave w owns rows w*16..w*16+15, all 48 cols (3 n-tiles).
// LDS rows padded to 136 bf16 (272 B): bank stride 4 -> only 2-way aliasing.
// ---------------------------------------------------------------------------
#define LDA 136
__global__ __launch_bounds__(256) void gemm_kernel(
    const float* __restrict__ x, const float* __restrict__ W,
    float* __restrict__ h, int N)
{
    __shared__ unsigned short As[64][LDA];   // As[m][k], bf16
    __shared__ unsigned short Bs[48][LDA];   // Bs[n][k], bf16 (W transposed)

    const int tid  = threadIdx.x;
    const int lane = tid & 63;
    const int wave = tid >> 6;
    const int lm   = lane & 15;     // row-in-tile (A) / col (B)
    const int kc   = lane >> 4;     // k-chunk 0..3
    const int m0   = blockIdx.x * 64;
    const int n0   = blockIdx.y * 48;

    // --- stage x -> As (convert fp32->bf16), vectorized: float4 in, 8B out
    for (int e = tid; e < 64 * 32; e += 256) {      // 64 rows x 32 float4
        int r = e >> 5, kq = e & 31;
        int gr = m0 + r;
        float4 v = (gr < N) ? ((const float4*)(x + (size_t)gr * F_IN))[kq]
                            : make_float4(0.f, 0.f, 0.f, 0.f);
        unsigned int lo = (unsigned int)f2bf(v.x) | ((unsigned int)f2bf(v.y) << 16);
        unsigned int hi = (unsigned int)f2bf(v.z) | ((unsigned int)f2bf(v.w) << 16);
        *(uint2*)&As[r][kq * 4] = make_uint2(lo, hi);
    }
    // --- stage W -> Bs transposed: Bs[n][k] = W[k][n0+n]
    for (int e = tid; e < 128 * 48; e += 256) {
        int k = e / 48, n = e % 48;
        Bs[n][k] = f2bf(W[k * HC + n0 + n]);
    }
    __syncthreads();

    floatx4 acc[3] = {};
    const int arow = wave * 16 + lm;
    #pragma unroll
    for (int ks = 0; ks < 4; ++ks) {
        bf16x8 a = *(const bf16x8*)&As[arow][ks * 32 + kc * 8];
        #pragma unroll
        for (int t = 0; t < 3; ++t) {
            bf16x8 b = *(const bf16x8*)&Bs[t * 16 + lm][ks * 32 + kc * 8];
            acc[t] = __builtin_amdgcn_mfma_f32_16x16x32_bf16(a, b, acc[t], 0, 0, 0);
        }
    }

    // C/D layout: col = lane&15, row = (lane>>4)*4 + reg   [m89-verified]
    #pragma unroll
    for (int t = 0; t < 3; ++t) {
        #pragma unroll
        for (int r = 0; r < 4; ++r) {
            int row = m0 + wave * 16 + kc * 4 + r;
            if (row < N) h[(size_t)row * HC + n0 + t * 16 + lm] = acc[t][r];
        }
    }
}

// ---------------------------------------------------------------------------
// K1b: a_src[n,hd] = <h[n,hd,:], att_src[hd,:]>, same for a_dst
// ---------------------------------------------------------------------------
__global__ void att_kernel(const float* __restrict__ h,
                           const float* __restrict__ att_src,
                           const float* __restrict__ att_dst,
                           float* __restrict__ a_src, float* __restrict__ a_dst,
                           int total)  // total = N * H_HEADS
{
    int g = blockIdx.x * blockDim.x + threadIdx.x;
    if (g >= total) return;
    int n = g / H_HEADS, head = g % H_HEADS;
    const float4* hv  = (const float4*)(h + (size_t)n * HC + head * C_CH);
    const float4* asv = (const float4*)(att_src + head * C_CH);
    const float4* adv = (const float4*)(att_dst + head * C_CH);
    float s = 0.f, d = 0.f;
    #pragma unroll
    for (int q = 0; q < 4; ++q) {
        float4 hq = hv[q], aq = asv[q], bq = adv[q];
        s += hq.x * aq.x + hq.y * aq.y + hq.z * aq.z + hq.w * aq.w;
        d += hq.x * bq.x + hq.y * bq.y + hq.z * bq.z + hq.w * bq.w;
    }
    a_src[g] = s;
    a_dst[g] = d;
}

// ---------------------------------------------------------------------------
// K2: denom[dst,hd] += exp(leakyrelu(a_src[src,hd] + a_dst[dst,hd]))
//     segment-max skipped: |e| small -> exp() safe; softmax shift-invariant.
// ---------------------------------------------------------------------------
__global__ void denom_kernel(const int* __restrict__ ei,
                             const float* __restrict__ a_src,
                             const float* __restrict__ a_dst,
                             float* __restrict__ denom,
                             int E, int Et)
{
    int g = blockIdx.x * blockDim.x + threadIdx.x;
    if (g >= Et * H_HEADS) return;
    int e = g / H_HEADS, hd = g % H_HEADS;
    int src, dst;
    if (e < E) { src = ei[e]; dst = ei[E + e]; }
    else       { src = dst = e - E; }          // self loops appended
    float v = a_src[src * H_HEADS + hd] + a_dst[dst * H_HEADS + hd];
    v = v > 0.f ? v : NEG_SLOPE * v;
    atomicAdd(&denom[dst * H_HEADS + hd], __expf(v));
}

// K2b: denom -> 1/(denom + 1e-16) in place
__global__ void inv_kernel(float* __restrict__ denom, int total)
{
    int g = blockIdx.x * blockDim.x + threadIdx.x;
    if (g >= total) return;
    denom[g] = 1.0f / (denom[g] + 1e-16f);
}

// ---------------------------------------------------------------------------
// K3: out[dst,c] += sum_h alpha[e,h] * h[src,h,c]
// ---------------------------------------------------------------------------
__global__ void aggregate_kernel(const int* __restrict__ ei,
                                 const float* __restrict__ a_src,
                                 const float* __restrict__ a_dst,
                                 const float* __restrict__ inv_denom,
                                 const float* __restrict__ h,
                                 float* __restrict__ out,
                                 int E, int Et)
{
    int g = blockIdx.x * blockDim.x + threadIdx.x;
    if (g >= Et * C_CH) return;
    int e = g >> 4, c = g & 15;
    int src, dst;
    if (e < E) { src = ei[e]; dst = ei[E + e]; }
    else       { src = dst = e - E; }
    const float* as = a_src + src * H_HEADS;
    const float* ad = a_dst + dst * H_HEADS;
    const float* id = inv_denom + dst * H_HEADS;
    const float* hs = h + (size_t)src * HC + c;
    float acc = 0.f;
    #pragma unroll
    for (int hd = 0; hd < H_HEADS; ++hd) {
        float v = as[hd] + ad[hd];
        v = v > 0.f ? v : NEG_SLOPE * v;
        float alpha = __expf(v) * id[hd];
        acc += alpha * hs[hd * C_CH];
    }
    atomicAdd(&out[dst * C_CH + c], acc);
}

// K4: out = tanh(out/H + bias), in place
__global__ void finalize_kernel(float* __restrict__ out,
                                const float* __restrict__ bias, int total)
{
    int g = blockIdx.x * blockDim.x + threadIdx.x;
    if (g >= total) return;
    out[g] = tanhf(out[g] * (1.0f / 33.0f) + bias[g & 15]);
}

// ---------------------------------------------------------------------------
extern "C" void kernel_launch(void* const* d_in, const int* in_sizes, int n_in,
                              void* d_out, int out_size, void* d_ws, size_t ws_size,
                              hipStream_t stream)
{
    const float* x       = (const float*)d_in[0];
    const int*   ei      = (const int*)  d_in[1];
    const float* W       = (const float*)d_in[2];
    const float* att_src = (const float*)d_in[3];
    const float* att_dst = (const float*)d_in[4];
    const float* bias    = (const float*)d_in[5];
    float* out = (float*)d_out;

    const int N  = in_sizes[0] / F_IN;   // 50000
    const int E  = in_sizes[1] / 2;      // 320000
    const int Et = E + N;                // with self loops

    // workspace layout (fp32): h | a_src | a_dst | denom  (~125.4 MB)
    float* h      = (float*)d_ws;
    float* a_src  = h + (size_t)N * HC;
    float* a_dst  = a_src + (size_t)N * H_HEADS;
    float* denom  = a_dst + (size_t)N * H_HEADS;

    hipMemsetAsync(d_out, 0, (size_t)out_size * sizeof(float), stream);
    hipMemsetAsync(denom, 0, (size_t)N * H_HEADS * sizeof(float), stream);

    dim3 g1((N + 63) / 64, HC / 48);     // 782 x 11
    gemm_kernel<<<g1, 256, 0, stream>>>(x, W, h, N);

    int totA = N * H_HEADS;
    att_kernel<<<(totA + 255) / 256, 256, 0, stream>>>(h, att_src, att_dst,
                                                       a_src, a_dst, totA);

    int totD = Et * H_HEADS;
    denom_kernel<<<(totD + 255) / 256, 256, 0, stream>>>(ei, a_src, a_dst,
                                                         denom, E, Et);

    inv_kernel<<<(totA + 255) / 256, 256, 0, stream>>>(denom, totA);

    int totG = Et * C_CH;
    aggregate_kernel<<<(totG + 255) / 256, 256, 0, stream>>>(ei, a_src, a_dst,
                                                             denom, h, out, E, Et);

    int totO = N * C_CH;
    finalize_kernel<<<(totO + 255) / 256, 256, 0, stream>>>(out, bias, totO);
}

// Round 3
// 332.440 us; speedup vs baseline: 1.4091x; 1.1256x over previous
//
#include <hip/hip_runtime.h>
#include <math.h>

#define H_HEADS 33
#define C_CH    16
#define HC      528      // H_HEADS * C_CH
#define F_IN    128
#define NEG_SLOPE 0.2f

typedef short  bf16x8  __attribute__((ext_vector_type(8)));
typedef float  floatx4 __attribute__((ext_vector_type(4)));

__device__ inline unsigned short f2bf(float f) {   // RNE float->bf16
    unsigned int u = __float_as_uint(f);
    unsigned int r = u + 0x7fffu + ((u >> 16) & 1u);
    return (unsigned short)(r >> 16);
}
__device__ inline float bf2f(unsigned short u) {
    return __uint_as_float((unsigned int)u << 16);
}

// ---------------------------------------------------------------------------
// K1: h_bf16 = bf16(x @ W)  via MFMA 16x16x32 bf16, BM=64, BN=48, K=128 in LDS.
// BN=48 == 3 heads exactly -> fused epilogue computes
//   a_src[row,head] = sum_c h[row,head,c]*att_src[head,c]   (16-lane reduce)
// from the fp32 accumulators (no att kernel, no atomics).
// ---------------------------------------------------------------------------
#define LDA 136
__global__ __launch_bounds__(256) void gemm_att_kernel(
    const float* __restrict__ x, const float* __restrict__ W,
    const float* __restrict__ att_src, const float* __restrict__ att_dst,
    unsigned short* __restrict__ hb,
    float* __restrict__ a_src, float* __restrict__ a_dst, int N)
{
    __shared__ unsigned short As[64][LDA];   // As[m][k], bf16
    __shared__ unsigned short Bs[48][LDA];   // Bs[n][k], bf16 (W transposed)

    const int tid  = threadIdx.x;
    const int lane = tid & 63;
    const int wave = tid >> 6;
    const int lm   = lane & 15;
    const int kc   = lane >> 4;
    const int m0   = blockIdx.x * 64;
    const int n0   = blockIdx.y * 48;

    for (int e = tid; e < 64 * 32; e += 256) {
        int r = e >> 5, kq = e & 31;
        int gr = m0 + r;
        float4 v = (gr < N) ? ((const float4*)(x + (size_t)gr * F_IN))[kq]
                            : make_float4(0.f, 0.f, 0.f, 0.f);
        unsigned int lo = (unsigned int)f2bf(v.x) | ((unsigned int)f2bf(v.y) << 16);
        unsigned int hi = (unsigned int)f2bf(v.z) | ((unsigned int)f2bf(v.w) << 16);
        *(uint2*)&As[r][kq * 4] = make_uint2(lo, hi);
    }
    for (int e = tid; e < 128 * 48; e += 256) {
        int k = e / 48, n = e % 48;
        Bs[n][k] = f2bf(W[k * HC + n0 + n]);
    }
    __syncthreads();

    floatx4 acc[3] = {};
    const int arow = wave * 16 + lm;
    #pragma unroll
    for (int ks = 0; ks < 4; ++ks) {
        bf16x8 a = *(const bf16x8*)&As[arow][ks * 32 + kc * 8];
        #pragma unroll
        for (int t = 0; t < 3; ++t) {
            bf16x8 b = *(const bf16x8*)&Bs[t * 16 + lm][ks * 32 + kc * 8];
            acc[t] = __builtin_amdgcn_mfma_f32_16x16x32_bf16(a, b, acc[t], 0, 0, 0);
        }
    }

    // C/D layout: col = lane&15, row = (lane>>4)*4 + reg
    #pragma unroll
    for (int t = 0; t < 3; ++t) {
        const int head = blockIdx.y * 3 + t;
        const float w_s = att_src[head * C_CH + lm];
        const float w_d = att_dst[head * C_CH + lm];
        #pragma unroll
        for (int r = 0; r < 4; ++r) {
            const int row = m0 + wave * 16 + kc * 4 + r;
            float s = acc[t][r] * w_s;
            float d = acc[t][r] * w_d;
            #pragma unroll
            for (int m = 8; m >= 1; m >>= 1) {   // reduce across the 16 lm lanes
                s += __shfl_xor(s, m);
                d += __shfl_xor(d, m);
            }
            if (row < N) {
                hb[(size_t)row * HC + n0 + t * 16 + lm] = f2bf(acc[t][r]);
                if (lm == 0) {
                    a_src[row * H_HEADS + head] = s;
                    a_dst[row * H_HEADS + head] = d;
                }
            }
        }
    }
}

// ---------------------------------------------------------------------------
// K2: denom[dst,hd] += exp(leakyrelu(a_src[src,hd] + a_dst[dst,hd]))
//     segment-max skipped: |e| small -> exp() safe; softmax shift-invariant.
// ---------------------------------------------------------------------------
__global__ void denom_kernel(const int* __restrict__ ei,
                             const float* __restrict__ a_src,
                             const float* __restrict__ a_dst,
                             float* __restrict__ denom,
                             int E, int Et)
{
    int g = blockIdx.x * blockDim.x + threadIdx.x;
    if (g >= Et * H_HEADS) return;
    int e = g / H_HEADS, hd = g % H_HEADS;
    int src, dst;
    if (e < E) { src = ei[e]; dst = ei[E + e]; }
    else       { src = dst = e - E; }          // self loops appended
    float v = a_src[src * H_HEADS + hd] + a_dst[dst * H_HEADS + hd];
    v = v > 0.f ? v : NEG_SLOPE * v;
    atomicAdd(&denom[dst * H_HEADS + hd], __expf(v));
}

// K2b: denom -> 1/(denom + 1e-16) in place
__global__ void inv_kernel(float* __restrict__ denom, int total)
{
    int g = blockIdx.x * blockDim.x + threadIdx.x;
    if (g >= total) return;
    denom[g] = 1.0f / (denom[g] + 1e-16f);
}

// ---------------------------------------------------------------------------
// K3: 16 edges/block. Phase 1: 16x33 alphas computed ONCE into LDS
// (was 16x redundant). Phase 2: lane (edge,c) gathers bf16 h row, fma with
// LDS-broadcast alpha, one 16-float atomic bundle per edge.
// ---------------------------------------------------------------------------
#define EPB 16
__global__ __launch_bounds__(256) void aggregate_kernel(
    const int* __restrict__ ei,
    const float* __restrict__ a_src, const float* __restrict__ a_dst,
    const float* __restrict__ inv_denom,
    const unsigned short* __restrict__ hb,
    float* __restrict__ out, int E, int Et)
{
    __shared__ int   s_src[EPB], s_dst[EPB];
    __shared__ float s_alpha[EPB][H_HEADS];

    const int tid = threadIdx.x;
    const int e0  = blockIdx.x * EPB;

    if (tid < EPB * 2) {
        int e = e0 + (tid & 15);
        int v = 0;
        if (e < Et) {
            if (e < E) v = (tid < EPB) ? ei[e] : ei[E + e];
            else       v = e - E;
        }
        if (tid < EPB) s_src[tid] = v; else s_dst[tid - EPB] = v;
    }
    __syncthreads();

    for (int i = tid; i < EPB * H_HEADS; i += 256) {
        int el = i / H_HEADS, hd = i - el * H_HEADS;
        if (e0 + el < Et) {
            int src = s_src[el], dst = s_dst[el];
            float v = a_src[src * H_HEADS + hd] + a_dst[dst * H_HEADS + hd];
            v = v > 0.f ? v : NEG_SLOPE * v;
            s_alpha[el][hd] = __expf(v) * inv_denom[dst * H_HEADS + hd];
        }
    }
    __syncthreads();

    const int el = tid >> 4, c = tid & 15;
    const int e = e0 + el;
    if (e >= Et) return;
    const int src = s_src[el], dst = s_dst[el];
    const unsigned short* hs = hb + (size_t)src * HC + c;
    float acc = 0.f;
    #pragma unroll
    for (int hd = 0; hd < H_HEADS; ++hd)
        acc += s_alpha[el][hd] * bf2f(hs[hd * C_CH]);
    atomicAdd(&out[dst * C_CH + c], acc);
}

// K4: out = tanh(out/H + bias), in place
__global__ void finalize_kernel(float* __restrict__ out,
                                const float* __restrict__ bias, int total)
{
    int g = blockIdx.x * blockDim.x + threadIdx.x;
    if (g >= total) return;
    out[g] = tanhf(out[g] * (1.0f / 33.0f) + bias[g & 15]);
}

// ---------------------------------------------------------------------------
extern "C" void kernel_launch(void* const* d_in, const int* in_sizes, int n_in,
                              void* d_out, int out_size, void* d_ws, size_t ws_size,
                              hipStream_t stream)
{
    const float* x       = (const float*)d_in[0];
    const int*   ei      = (const int*)  d_in[1];
    const float* W       = (const float*)d_in[2];
    const float* att_src = (const float*)d_in[3];
    const float* att_dst = (const float*)d_in[4];
    const float* bias    = (const float*)d_in[5];
    float* out = (float*)d_out;

    const int N  = in_sizes[0] / F_IN;   // 50000
    const int E  = in_sizes[1] / 2;      // 320000
    const int Et = E + N;                // with self loops

    // workspace: h_bf16 (52.8MB) | a_src | a_dst | denom (3 x 6.6MB)
    unsigned short* hb = (unsigned short*)d_ws;
    float* a_src  = (float*)(hb + (size_t)N * HC);
    float* a_dst  = a_src + (size_t)N * H_HEADS;
    float* denom  = a_dst + (size_t)N * H_HEADS;

    hipMemsetAsync(d_out, 0, (size_t)out_size * sizeof(float), stream);
    hipMemsetAsync(denom, 0, (size_t)N * H_HEADS * sizeof(float), stream);

    dim3 g1((N + 63) / 64, HC / 48);     // 782 x 11
    gemm_att_kernel<<<g1, 256, 0, stream>>>(x, W, att_src, att_dst,
                                            hb, a_src, a_dst, N);

    int totD = Et * H_HEADS;
    denom_kernel<<<(totD + 255) / 256, 256, 0, stream>>>(ei, a_src, a_dst,
                                                         denom, E, Et);

    int totA = N * H_HEADS;
    inv_kernel<<<(totA + 255) / 256, 256, 0, stream>>>(denom, totA);

    aggregate_kernel<<<(Et + EPB - 1) / EPB, 256, 0, stream>>>(
        ei, a_src, a_dst, denom, hb, out, E, Et);

    int totO = N * C_CH;
    finalize_kernel<<<(totO + 255) / 256, 256, 0, stream>>>(out, bias, totO);
}

// Round 4
// 318.795 us; speedup vs baseline: 1.4694x; 1.0428x over previous
//
#include <hip/hip_runtime.h>
#include <math.h>

#define H_HEADS 33
#define C_CH    16
#define HC      528      // H_HEADS * C_CH
#define F_IN    128
#define NEG_SLOPE 0.2f

typedef short  bf16x8  __attribute__((ext_vector_type(8)));
typedef float  floatx4 __attribute__((ext_vector_type(4)));

__device__ inline unsigned short f2bf(float f) {   // RNE float->bf16
    unsigned int u = __float_as_uint(f);
    unsigned int r = u + 0x7fffu + ((u >> 16) & 1u);
    return (unsigned short)(r >> 16);
}
__device__ inline float bf2f(unsigned short u) {
    return __uint_as_float((unsigned int)u << 16);
}

// ---------------------------------------------------------------------------
// K0a: xb = bf16(x), [N][128]. One thread per 4 floats.
// ---------------------------------------------------------------------------
__global__ void cvt_x_kernel(const float* __restrict__ x,
                             unsigned short* __restrict__ xb, int total4)
{
    int g = blockIdx.x * blockDim.x + threadIdx.x;
    if (g >= total4) return;
    float4 v = ((const float4*)x)[g];
    unsigned int lo = (unsigned int)f2bf(v.x) | ((unsigned int)f2bf(v.y) << 16);
    unsigned int hi = (unsigned int)f2bf(v.z) | ((unsigned int)f2bf(v.w) << 16);
    ((uint2*)xb)[g] = make_uint2(lo, hi);
}

// ---------------------------------------------------------------------------
// K0b: Wt = bf16(W^T), [528][128]. Coalesced read, scattered 2B write (tiny,
// all sectors fully covered -> L2 merges).
// ---------------------------------------------------------------------------
__global__ void cvt_w_kernel(const float* __restrict__ W,
                             unsigned short* __restrict__ Wt)
{
    int g = blockIdx.x * blockDim.x + threadIdx.x;
    if (g >= F_IN * HC) return;
    int k = g / HC, n = g % HC;
    Wt[n * F_IN + k] = f2bf(W[g]);
}

// ---------------------------------------------------------------------------
// K1: h_bf16 = xb @ Wt^T via MFMA 16x16x32 bf16. BM=64, BN=48, K=128 in LDS.
// Staging is pure bf16 row copies (uint4) — no converts, no transpose, no
// LDS write conflicts. LDA=136 shorts: frag ds_read_b128 at 2-way = free.
// BN=48 == 3 heads -> fused epilogue reduces a_src/a_dst from fp32 acc.
// ---------------------------------------------------------------------------
#define LDA 136
__global__ __launch_bounds__(256) void gemm_att_kernel(
    const unsigned short* __restrict__ xb, const unsigned short* __restrict__ Wt,
    const float* __restrict__ att_src, const float* __restrict__ att_dst,
    unsigned short* __restrict__ hb,
    float* __restrict__ a_src, float* __restrict__ a_dst, int N)
{
    __shared__ unsigned short As[64][LDA];   // As[m][k]
    __shared__ unsigned short Bs[48][LDA];   // Bs[n][k] (= Wt rows)

    const int tid  = threadIdx.x;
    const int lane = tid & 63;
    const int wave = tid >> 6;
    const int lm   = lane & 15;
    const int kc   = lane >> 4;
    const int m0   = blockIdx.x * 64;
    const int n0   = blockIdx.y * 48;

    // stage As: 64 rows x 16 uint4 chunks (256B/row)
    for (int e = tid; e < 64 * 16; e += 256) {
        int r = e >> 4, c = e & 15;
        int gr = m0 + r;
        uint4 v = (gr < N) ? ((const uint4*)(xb + (size_t)gr * F_IN))[c]
                           : make_uint4(0, 0, 0, 0);
        *(uint4*)&As[r][c * 8] = v;
    }
    // stage Bs: 48 rows x 16 uint4 chunks
    for (int e = tid; e < 48 * 16; e += 256) {
        int r = e >> 4, c = e & 15;
        uint4 v = ((const uint4*)(Wt + (size_t)(n0 + r) * F_IN))[c];
        *(uint4*)&Bs[r][c * 8] = v;
    }
    __syncthreads();

    floatx4 acc[3] = {};
    const int arow = wave * 16 + lm;
    #pragma unroll
    for (int ks = 0; ks < 4; ++ks) {
        bf16x8 a = *(const bf16x8*)&As[arow][ks * 32 + kc * 8];
        #pragma unroll
        for (int t = 0; t < 3; ++t) {
            bf16x8 b = *(const bf16x8*)&Bs[t * 16 + lm][ks * 32 + kc * 8];
            acc[t] = __builtin_amdgcn_mfma_f32_16x16x32_bf16(a, b, acc[t], 0, 0, 0);
        }
    }

    // C/D layout: col = lane&15, row = (lane>>4)*4 + reg
    #pragma unroll
    for (int t = 0; t < 3; ++t) {
        const int head = blockIdx.y * 3 + t;
        const float w_s = att_src[head * C_CH + lm];
        const float w_d = att_dst[head * C_CH + lm];
        #pragma unroll
        for (int r = 0; r < 4; ++r) {
            const int row = m0 + wave * 16 + kc * 4 + r;
            float s = acc[t][r] * w_s;
            float d = acc[t][r] * w_d;
            #pragma unroll
            for (int m = 8; m >= 1; m >>= 1) {   // reduce across the 16 lm lanes
                s += __shfl_xor(s, m);
                d += __shfl_xor(d, m);
            }
            if (row < N) {
                hb[(size_t)row * HC + n0 + t * 16 + lm] = f2bf(acc[t][r]);
                if (lm == 0) {
                    a_src[row * H_HEADS + head] = s;
                    a_dst[row * H_HEADS + head] = d;
                }
            }
        }
    }
}

// ---------------------------------------------------------------------------
// K2: denom[dst,hd] += exp(leakyrelu(a_src[src,hd] + a_dst[dst,hd]))
//     segment-max skipped: |e| small -> exp() safe; softmax shift-invariant.
// ---------------------------------------------------------------------------
__global__ void denom_kernel(const int* __restrict__ ei,
                             const float* __restrict__ a_src,
                             const float* __restrict__ a_dst,
                             float* __restrict__ denom,
                             int E, int Et)
{
    int g = blockIdx.x * blockDim.x + threadIdx.x;
    if (g >= Et * H_HEADS) return;
    int e = g / H_HEADS, hd = g % H_HEADS;
    int src, dst;
    if (e < E) { src = ei[e]; dst = ei[E + e]; }
    else       { src = dst = e - E; }          // self loops appended
    float v = a_src[src * H_HEADS + hd] + a_dst[dst * H_HEADS + hd];
    v = v > 0.f ? v : NEG_SLOPE * v;
    atomicAdd(&denom[dst * H_HEADS + hd], __expf(v));
}

// K2b: denom -> 1/(denom + 1e-16) in place
__global__ void inv_kernel(float* __restrict__ denom, int total)
{
    int g = blockIdx.x * blockDim.x + threadIdx.x;
    if (g >= total) return;
    denom[g] = 1.0f / (denom[g] + 1e-16f);
}

// ---------------------------------------------------------------------------
// K3: 16 edges/block. Phase 1: 16x33 alphas computed once into LDS.
// Phase 2: lane (edge,c) gathers bf16 h row, fma with LDS alpha, one
// 16-float atomic bundle per edge.
// ---------------------------------------------------------------------------
#define EPB 16
__global__ __launch_bounds__(256) void aggregate_kernel(
    const int* __restrict__ ei,
    const float* __restrict__ a_src, const float* __restrict__ a_dst,
    const float* __restrict__ inv_denom,
    const unsigned short* __restrict__ hb,
    float* __restrict__ out, int E, int Et)
{
    __shared__ int   s_src[EPB], s_dst[EPB];
    __shared__ float s_alpha[EPB][H_HEADS];

    const int tid = threadIdx.x;
    const int e0  = blockIdx.x * EPB;

    if (tid < EPB * 2) {
        int e = e0 + (tid & 15);
        int v = 0;
        if (e < Et) {
            if (e < E) v = (tid < EPB) ? ei[e] : ei[E + e];
            else       v = e - E;
        }
        if (tid < EPB) s_src[tid] = v; else s_dst[tid - EPB] = v;
    }
    __syncthreads();

    for (int i = tid; i < EPB * H_HEADS; i += 256) {
        int el = i / H_HEADS, hd = i - el * H_HEADS;
        if (e0 + el < Et) {
            int src = s_src[el], dst = s_dst[el];
            float v = a_src[src * H_HEADS + hd] + a_dst[dst * H_HEADS + hd];
            v = v > 0.f ? v : NEG_SLOPE * v;
            s_alpha[el][hd] = __expf(v) * inv_denom[dst * H_HEADS + hd];
        }
    }
    __syncthreads();

    const int el = tid >> 4, c = tid & 15;
    const int e = e0 + el;
    if (e >= Et) return;
    const int src = s_src[el], dst = s_dst[el];
    const unsigned short* hs = hb + (size_t)src * HC + c;
    float acc = 0.f;
    #pragma unroll
    for (int hd = 0; hd < H_HEADS; ++hd)
        acc += s_alpha[el][hd] * bf2f(hs[hd * C_CH]);
    atomicAdd(&out[dst * C_CH + c], acc);
}

// K4: out = tanh(out/H + bias), in place
__global__ void finalize_kernel(float* __restrict__ out,
                                const float* __restrict__ bias, int total)
{
    int g = blockIdx.x * blockDim.x + threadIdx.x;
    if (g >= total) return;
    out[g] = tanhf(out[g] * (1.0f / 33.0f) + bias[g & 15]);
}

// ---------------------------------------------------------------------------
extern "C" void kernel_launch(void* const* d_in, const int* in_sizes, int n_in,
                              void* d_out, int out_size, void* d_ws, size_t ws_size,
                              hipStream_t stream)
{
    const float* x       = (const float*)d_in[0];
    const int*   ei      = (const int*)  d_in[1];
    const float* W       = (const float*)d_in[2];
    const float* att_src = (const float*)d_in[3];
    const float* att_dst = (const float*)d_in[4];
    const float* bias    = (const float*)d_in[5];
    float* out = (float*)d_out;

    const int N  = in_sizes[0] / F_IN;   // 50000
    const int E  = in_sizes[1] / 2;      // 320000
    const int Et = E + N;                // with self loops

    // workspace: hb (52.8MB) | a_src | a_dst | denom (3x6.6MB) | xb (12.8MB) | Wt
    unsigned short* hb = (unsigned short*)d_ws;
    float* a_src  = (float*)(hb + (size_t)N * HC);
    float* a_dst  = a_src + (size_t)N * H_HEADS;
    float* denom  = a_dst + (size_t)N * H_HEADS;
    unsigned short* xb = (unsigned short*)(denom + (size_t)N * H_HEADS);
    unsigned short* Wt = xb + (size_t)N * F_IN;

    hipMemsetAsync(d_out, 0, (size_t)out_size * sizeof(float), stream);
    hipMemsetAsync(denom, 0, (size_t)N * H_HEADS * sizeof(float), stream);

    int total4 = N * F_IN / 4;
    cvt_x_kernel<<<(total4 + 255) / 256, 256, 0, stream>>>(x, xb, total4);
    cvt_w_kernel<<<(F_IN * HC + 255) / 256, 256, 0, stream>>>(W, Wt);

    dim3 g1((N + 63) / 64, HC / 48);     // 782 x 11
    gemm_att_kernel<<<g1, 256, 0, stream>>>(xb, Wt, att_src, att_dst,
                                            hb, a_src, a_dst, N);

    int totD = Et * H_HEADS;
    denom_kernel<<<(totD + 255) / 256, 256, 0, stream>>>(ei, a_src, a_dst,
                                                         denom, E, Et);

    int totA = N * H_HEADS;
    inv_kernel<<<(totA + 255) / 256, 256, 0, stream>>>(denom, totA);

    aggregate_kernel<<<(Et + EPB - 1) / EPB, 256, 0, stream>>>(
        ei, a_src, a_dst, denom, hb, out, E, Et);

    int totO = N * C_CH;
    finalize_kernel<<<(totO + 255) / 256, 256, 0, stream>>>(out, bias, totO);
}